// Round 9
// baseline (272.554 us; speedup 1.0000x reference)
//
#include <hip/hip_runtime.h>

// ==== DIAGNOSTIC ROUND 2: grid-replication amplification (no code distortion)
// prep x48, fused x8 (id-offset per replica -> cold gathers), tower x24.
// Per-block code identical to R8; replicas only remap blockIdx and gate
// side effects to replica 0 where needed.

#define B_SZ  16384
#define F_SZ  20
#define V_SZ  100000
#define E_SZ  32
#define DBOT  640
#define D1    512
#define D2    256
#define T1D   128
#define T2D   64
#define NDOM  4

#define REP_PREP  48
#define REP_FUSED 8
#define REP_TOWER 24

typedef __bf16 bf16x8 __attribute__((ext_vector_type(8)));
typedef float  f32x4  __attribute__((ext_vector_type(4)));

#define MFMA(a, b, c) __builtin_amdgcn_mfma_f32_16x16x32_bf16((a), (b), (c), 0, 0, 0)

// ---------------------------------------------------------------------------
__global__ __launch_bounds__(256) void k_prep(const float* __restrict__ W1,
                                              const float* __restrict__ W2,
                                              const float* __restrict__ TW1,
                                              const float* __restrict__ TW2,
                                              __bf16* __restrict__ W1P,
                                              __bf16* __restrict__ W2P,
                                              __bf16* __restrict__ TW1P,
                                              __bf16* __restrict__ TW2P,
                                              int* __restrict__ cnt) {
  int bid = blockIdx.x % 305, tid = threadIdx.x;   // replicas write same data
  const float* src; __bf16* dst; int n, k, N;
  if (bid < 160) {
    long g = (long)bid * 256 + tid;
    int lane = g & 63; int kkg = (int)((g >> 6) % 20); int ntile = (int)(g / 1280);
    n = ntile * 16 + (lane & 15); k = kkg * 32 + ((lane >> 4) << 3);
    src = W1; N = D1; dst = W1P + g * 8;
  } else if (bid < 224) {
    long g = (long)(bid - 160) * 256 + tid;
    int lane = g & 63; int kkg = (int)((g >> 6) & 15); int ntile = (int)(g >> 10);
    n = ntile * 16 + (lane & 15); k = kkg * 32 + ((lane >> 4) << 3);
    src = W2; N = D2; dst = W2P + g * 8;
  } else if (bid < 288) {
    long g = (long)(bid - 224) * 256 + tid;
    int d = (int)(g >> 12); long r = g & 4095;
    int lane = r & 63; int kkg = (int)((r >> 6) & 7); int ntile = (int)(r >> 9);
    n = ntile * 16 + (lane & 15); k = kkg * 32 + ((lane >> 4) << 3);
    src = TW1 + (long)d * D2 * T1D; N = T1D;
    dst = TW1P + ((long)(d * 64 + ntile * 8 + kkg) * 64 + lane) * 8;
  } else if (bid < 304) {
    long g = (long)(bid - 288) * 256 + tid;
    int d = (int)(g >> 10); long r = g & 1023;
    int lane = r & 63; int kkg = (int)((r >> 6) & 3); int ntile = (int)(r >> 8);
    n = ntile * 16 + (lane & 15); k = kkg * 32 + ((lane >> 4) << 3);
    src = TW2 + (long)d * T1D * T2D; N = T2D;
    dst = TW2P + ((long)(d * 16 + ntile * 4 + kkg) * 64 + lane) * 8;
  } else {
    if (tid < NDOM) cnt[tid] = 0;
    return;
  }
  bf16x8 o;
#pragma unroll
  for (int e = 0; e < 8; ++e) o[e] = (__bf16)src[(long)(k + e) * N + n];
  *(bf16x8*)dst = o;
}

// ---------------------------------------------------------------------------
// Fused (R8 per-block code).  Replica r: gather ids offset by r*4999 (cold
// rows, same statistics); partition + h2 store gated to replica 0.
// ---------------------------------------------------------------------------
__global__ __launch_bounds__(512) void k_fused(const int* __restrict__ fids,
                                               const int* __restrict__ dom,
                                               const float* __restrict__ emb,
                                               const __bf16* __restrict__ W1P,
                                               const float* __restrict__ b1,
                                               const __bf16* __restrict__ W2P,
                                               const float* __restrict__ b2,
                                               __bf16* __restrict__ h2,
                                               int* __restrict__ cnt,
                                               int* __restrict__ lists) {
  __shared__ int    ids_lds[64 * F_SZ];
  __shared__ __bf16 sA[2][64 * 64];
  __shared__ __bf16 h1[64 * D1];

  int rep = blockIdx.x >> 8;          // 0..7
  int bid = blockIdx.x & 255;
  int repoff = rep * 4999;
  int tid = threadIdx.x;
  int lane = tid & 63, w = tid >> 6;
  int lrow = lane & 15, kq = lane >> 4;
  int m0 = bid * 64;

  if (rep == 0 && bid < 64 && tid < 256) {
    int i = bid * 256 + tid;
    int d = dom[i];
    int pl = tid & 63;
#pragma unroll
    for (int dd = 0; dd < NDOM; ++dd) {
      unsigned long long md = __ballot(d == dd);
      if (d == dd) {
        int myoff = __popcll(md & ((1ull << pl) - 1ull));
        int leader = __ffsll((long long)md) - 1;
        int base = 0;
        if (pl == leader) base = atomicAdd(&cnt[dd], __popcll(md));
        base = __shfl(base, leader);
        lists[dd * B_SZ + base + myoff] = i;
      }
    }
  }

  for (int i = tid; i < 64 * F_SZ; i += 512) ids_lds[i] = fids[m0 * F_SZ + i];
  __syncthreads();

  int srow = tid >> 3, sc = tid & 7;
  int sbyte = srow * 128 + ((sc ^ (srow & 7)) << 4);
  int fsub = sc >> 2, esub = (sc & 3) << 3;

#define GID(F) ({ int _i = ids_lds[srow * F_SZ + (F)] + repoff;              \
                  if (_i >= V_SZ) _i -= V_SZ; _i; })

  float4 g0a, g1a, g0b, g1b, g0c, g1c;
  {
    int id = GID(fsub);
    const float* p = emb + ((long)fsub * V_SZ + id) * E_SZ + esub;
    g0a = *(const float4*)p; g1a = *(const float4*)(p + 4);
  }
  {
    int id = GID(2 + fsub);
    const float* p = emb + ((long)(2 + fsub) * V_SZ + id) * E_SZ + esub;
    g0b = *(const float4*)p; g1b = *(const float4*)(p + 4);
  }
  {
    int id = GID(4 + fsub);
    const float* p = emb + ((long)(4 + fsub) * V_SZ + id) * E_SZ + esub;
    g0c = *(const float4*)p; g1c = *(const float4*)(p + 4);
  }
  bf16x8 bfA[8], bfB[8];
#pragma unroll
  for (int ni = 0; ni < 4; ++ni)
#pragma unroll
    for (int kk = 0; kk < 2; ++kk)
      bfA[ni * 2 + kk] = *(const bf16x8*)(W1P +
          ((long)((w * 4 + ni) * 20 + kk) * 64 + lane) * 8);

  f32x4 acc[4][4] = {};

#define BODY(S, G0, G1, BC, BN)                                              \
    {                                                                        \
      bf16x8 o;                                                              \
      o[0]=(__bf16)G0.x; o[1]=(__bf16)G0.y; o[2]=(__bf16)G0.z; o[3]=(__bf16)G0.w; \
      o[4]=(__bf16)G1.x; o[5]=(__bf16)G1.y; o[6]=(__bf16)G1.z; o[7]=(__bf16)G1.w; \
      *(bf16x8*)((char*)sA + ((S) & 1) * 8192 + sbyte) = o;                  \
      asm volatile("s_waitcnt lgkmcnt(0)" ::: "memory");                     \
      __builtin_amdgcn_s_barrier();                                          \
      __builtin_amdgcn_sched_barrier(0);                                     \
      const char* sAb = (const char*)sA + ((S) & 1) * 8192;                  \
      bf16x8 af[2][4];                                                       \
      _Pragma("unroll")                                                      \
      for (int kk = 0; kk < 2; ++kk)                                         \
        _Pragma("unroll")                                                    \
        for (int mi = 0; mi < 4; ++mi) {                                     \
          int byte = ((mi * 16 + lrow) * 128 + (kk * 32 + kq * 8) * 2) ^ ((lrow & 7) << 4); \
          af[kk][mi] = *(const bf16x8*)(sAb + byte);                         \
        }                                                                    \
      _Pragma("unroll")                                                      \
      for (int kk = 0; kk < 2; ++kk)                                         \
        _Pragma("unroll")                                                    \
        for (int ni = 0; ni < 4; ++ni)                                       \
          _Pragma("unroll")                                                  \
          for (int mi = 0; mi < 4; ++mi)                                     \
            acc[mi][ni] = MFMA(af[kk][mi], BC[ni * 2 + kk], acc[mi][ni]);    \
      if ((S) + 1 < 10) {                                                    \
        _Pragma("unroll")                                                    \
        for (int ni = 0; ni < 4; ++ni)                                       \
          _Pragma("unroll")                                                  \
          for (int kk = 0; kk < 2; ++kk)                                     \
            BN[ni * 2 + kk] = *(const bf16x8*)(W1P +                         \
                ((long)((w * 4 + ni) * 20 + ((S) + 1) * 2 + kk) * 64 + lane) * 8); \
      }                                                                      \
      if ((S) + 3 < 10) {                                                    \
        int f = 2 * ((S) + 3) + fsub;                                        \
        int id = GID(f);                                                     \
        const float* p = emb + ((long)f * V_SZ + id) * E_SZ + esub;          \
        G0 = *(const float4*)p; G1 = *(const float4*)(p + 4);                \
      }                                                                      \
    }

  BODY(0, g0a, g1a, bfA, bfB)
  BODY(1, g0b, g1b, bfB, bfA)
  BODY(2, g0c, g1c, bfA, bfB)
  BODY(3, g0a, g1a, bfB, bfA)
  BODY(4, g0b, g1b, bfA, bfB)
  BODY(5, g0c, g1c, bfB, bfA)
  BODY(6, g0a, g1a, bfA, bfB)
  BODY(7, g0b, g1b, bfB, bfA)
  BODY(8, g0c, g1c, bfA, bfB)
  BODY(9, g0a, g1a, bfB, bfA)
#undef BODY
#undef GID

  // h1 = relu(. + b1) -> LDS
#pragma unroll
  for (int ni = 0; ni < 4; ++ni) {
    int col = w * 64 + ni * 16 + lrow;
    float bv = b1[col];
#pragma unroll
    for (int mi = 0; mi < 4; ++mi) {
#pragma unroll
      for (int r = 0; r < 4; ++r) {
        int row = mi * 16 + kq * 4 + r;
        float v = acc[mi][ni][r] + bv;
        v = v > 0.f ? v : 0.f;
        int byte = (row * 1024 + col * 2) ^ ((row & 7) << 4);
        *(__bf16*)((char*)h1 + byte) = (__bf16)v;
      }
    }
  }
  __syncthreads();

  // GEMM2
  f32x4 acc2[4][2] = {};
  for (int kkg = 0; kkg < 16; ++kkg) {
    bf16x8 a2[4];
#pragma unroll
    for (int mi = 0; mi < 4; ++mi) {
      int byte = ((mi * 16 + lrow) * 1024 + kkg * 64 + kq * 16) ^ ((lrow & 7) << 4);
      a2[mi] = *(const bf16x8*)((const char*)h1 + byte);
    }
#pragma unroll
    for (int ni = 0; ni < 2; ++ni) {
      bf16x8 bfr = *(const bf16x8*)(W2P +
          ((long)((w * 2 + ni) * 16 + kkg) * 64 + lane) * 8);
#pragma unroll
      for (int mi = 0; mi < 4; ++mi)
        acc2[mi][ni] = MFMA(a2[mi], bfr, acc2[mi][ni]);
    }
  }

  // h2 store: replica 0 only (replicas used different ids -> different data)
  if (rep == 0) {
#pragma unroll
    for (int ni = 0; ni < 2; ++ni) {
      int col = w * 32 + ni * 16 + lrow;
      float bv = b2[col];
#pragma unroll
      for (int mi = 0; mi < 4; ++mi) {
#pragma unroll
        for (int r = 0; r < 4; ++r) {
          long row = m0 + mi * 16 + kq * 4 + r;
          float v = acc2[mi][ni][r] + bv;
          v = v > 0.f ? v : 0.f;
          h2[row * D2 + col] = (__bf16)v;
        }
      }
    }
  } else {
    // keep the computation live for non-storing replicas
    asm volatile("" :: "v"(acc2[0][0][0]), "v"(acc2[3][1][3]));
  }
}

// ---------------------------------------------------------------------------
// Tower: replicas recompute + rewrite identical values (benign).
// ---------------------------------------------------------------------------
__global__ __launch_bounds__(256) void k_tower(const __bf16* __restrict__ h2,
                                               const __bf16* __restrict__ TW1P,
                                               const __bf16* __restrict__ TW2P,
                                               const float* __restrict__ Tb1,
                                               const float* __restrict__ Tb2,
                                               const float* __restrict__ TW3,
                                               const float* __restrict__ Tb3,
                                               const int* __restrict__ cnt,
                                               const int* __restrict__ lists,
                                               float* __restrict__ out) {
  __shared__ __bf16 t_lds[4][16 * 128];
  int d  = blockIdx.y;
  int nc = cnt[d];
  int base = (blockIdx.x % 80) * 64;
  if (base >= nc) return;

  int tid  = threadIdx.x;
  int lane = tid & 63;
  int w    = tid >> 6;
  int row  = lane & 15;
  int kq   = lane >> 4;
  int slot = base + w * 16 + row;
  bool valid = slot < nc;
  int m0r = lists[d * B_SZ + (valid ? slot : 0)];

  bf16x8 a1[8];
#pragma unroll
  for (int kk = 0; kk < 8; ++kk)
    a1[kk] = *(const bf16x8*)(h2 + (long)m0r * D2 + kk * 32 + kq * 8);

  f32x4 acc1[8] = {};
#pragma unroll
  for (int kk = 0; kk < 8; ++kk) {
#pragma unroll
    for (int ni = 0; ni < 8; ++ni) {
      bf16x8 b = *(const bf16x8*)(TW1P +
          ((long)(d * 64 + ni * 8 + kk) * 64 + lane) * 8);
      acc1[ni] = MFMA(a1[kk], b, acc1[ni]);
    }
  }
#pragma unroll
  for (int ni = 0; ni < 8; ++ni) {
    float bv = Tb1[d * T1D + ni * 16 + row];
#pragma unroll
    for (int r = 0; r < 4; ++r) {
      float v = acc1[ni][r] + bv;
      v = v > 0.f ? v : 0.f;
      t_lds[w][(kq * 4 + r) * 128 + ni * 16 + row] = (__bf16)v;
    }
  }
  asm volatile("s_waitcnt lgkmcnt(0)" ::: "memory");

  bf16x8 a2[4];
#pragma unroll
  for (int kk = 0; kk < 4; ++kk)
    a2[kk] = *(const bf16x8*)(&t_lds[w][row * 128 + kk * 32 + kq * 8]);
  f32x4 acc2[4] = {};
#pragma unroll
  for (int kk = 0; kk < 4; ++kk) {
#pragma unroll
    for (int ni = 0; ni < 4; ++ni) {
      bf16x8 b = *(const bf16x8*)(TW2P +
          ((long)(d * 16 + ni * 4 + kk) * 64 + lane) * 8);
      acc2[ni] = MFMA(a2[kk], b, acc2[ni]);
    }
  }
  asm volatile("s_waitcnt lgkmcnt(0)" ::: "memory");
#pragma unroll
  for (int ni = 0; ni < 4; ++ni) {
    float bv = Tb2[d * T2D + ni * 16 + row];
#pragma unroll
    for (int r = 0; r < 4; ++r) {
      float v = acc2[ni][r] + bv;
      v = v > 0.f ? v : 0.f;
      t_lds[w][(kq * 4 + r) * 64 + ni * 16 + row] = (__bf16)v;
    }
  }
  asm volatile("s_waitcnt lgkmcnt(0)" ::: "memory");

  float s = 0.f;
#pragma unroll
  for (int j = 0; j < 16; ++j)
    s += (float)t_lds[w][row * 64 + kq * 16 + j] * TW3[d * T2D + kq * 16 + j];
  s += __shfl_xor(s, 16);
  s += __shfl_xor(s, 32);
  s += Tb3[d];
  if (valid && kq == 0)
    out[m0r] = 1.0f / (1.0f + expf(-s));
}

// ---------------------------------------------------------------------------
extern "C" void kernel_launch(void* const* d_in, const int* in_sizes, int n_in,
                              void* d_out, int out_size, void* d_ws, size_t ws_size,
                              hipStream_t stream) {
  const int*   fids = (const int*)d_in[0];
  const int*   dom  = (const int*)d_in[1];
  const float* emb  = (const float*)d_in[2];
  const float* W1   = (const float*)d_in[3];
  const float* b1   = (const float*)d_in[4];
  const float* W2   = (const float*)d_in[5];
  const float* b2   = (const float*)d_in[6];
  const float* TW1  = (const float*)d_in[7];
  const float* Tb1  = (const float*)d_in[8];
  const float* TW2  = (const float*)d_in[9];
  const float* Tb2  = (const float*)d_in[10];
  const float* TW3  = (const float*)d_in[11];
  const float* Tb3  = (const float*)d_in[12];
  float* out = (float*)d_out;

  char* ws = (char*)d_ws;
  __bf16* W1P   = (__bf16*)(ws);
  __bf16* W2P   = (__bf16*)(ws + 655360);
  __bf16* TW1P  = (__bf16*)(ws + 917504);
  __bf16* TW2P  = (__bf16*)(ws + 1179648);
  __bf16* h2    = (__bf16*)(ws + 1245184);
  int*    lists = (int*)(ws + 9633792);
  int*    cnt   = (int*)(ws + 9895936);

  k_prep<<<305 * REP_PREP, 256, 0, stream>>>(W1, W2, TW1, TW2,
                                             W1P, W2P, TW1P, TW2P, cnt);
  k_fused<<<256 * REP_FUSED, 512, 0, stream>>>(fids, dom, emb, W1P, b1,
                                               W2P, b2, h2, cnt, lists);
  k_tower<<<dim3(80 * REP_TOWER, NDOM), 256, 0, stream>>>(h2, TW1P, TW2P,
                                                          Tb1, Tb2, TW3, Tb3,
                                                          cnt, lists, out);
}

// Round 10
// 53.163 us; speedup vs baseline: 5.1267x; 5.1267x over previous
//
#include <hip/hip_runtime.h>

#define B_SZ  16384
#define F_SZ  20
#define V_SZ  100000
#define E_SZ  32
#define DBOT  640
#define D1    512
#define D2    256
#define T1D   128
#define T2D   64
#define NDOM  4

typedef __bf16 bf16x8 __attribute__((ext_vector_type(8)));
typedef float  f32x4  __attribute__((ext_vector_type(4)));

#define MFMA(a, b, c) __builtin_amdgcn_mfma_f32_16x16x32_bf16((a), (b), (c), 0, 0, 0)

// ---------------------------------------------------------------------------
// Prep: pack all weights into MFMA-fragment order bf16 (unchanged).
// ---------------------------------------------------------------------------
__global__ __launch_bounds__(256) void k_prep(const float* __restrict__ W1,
                                              const float* __restrict__ W2,
                                              const float* __restrict__ TW1,
                                              const float* __restrict__ TW2,
                                              __bf16* __restrict__ W1P,
                                              __bf16* __restrict__ W2P,
                                              __bf16* __restrict__ TW1P,
                                              __bf16* __restrict__ TW2P,
                                              int* __restrict__ cnt) {
  int bid = blockIdx.x, tid = threadIdx.x;
  const float* src; __bf16* dst; int n, k, N;
  if (bid < 160) {
    long g = (long)bid * 256 + tid;
    int lane = g & 63; int kkg = (int)((g >> 6) % 20); int ntile = (int)(g / 1280);
    n = ntile * 16 + (lane & 15); k = kkg * 32 + ((lane >> 4) << 3);
    src = W1; N = D1; dst = W1P + g * 8;
  } else if (bid < 224) {
    long g = (long)(bid - 160) * 256 + tid;
    int lane = g & 63; int kkg = (int)((g >> 6) & 15); int ntile = (int)(g >> 10);
    n = ntile * 16 + (lane & 15); k = kkg * 32 + ((lane >> 4) << 3);
    src = W2; N = D2; dst = W2P + g * 8;
  } else if (bid < 288) {
    long g = (long)(bid - 224) * 256 + tid;
    int d = (int)(g >> 12); long r = g & 4095;
    int lane = r & 63; int kkg = (int)((r >> 6) & 7); int ntile = (int)(r >> 9);
    n = ntile * 16 + (lane & 15); k = kkg * 32 + ((lane >> 4) << 3);
    src = TW1 + (long)d * D2 * T1D; N = T1D;
    dst = TW1P + ((long)(d * 64 + ntile * 8 + kkg) * 64 + lane) * 8;
  } else if (bid < 304) {
    long g = (long)(bid - 288) * 256 + tid;
    int d = (int)(g >> 10); long r = g & 1023;
    int lane = r & 63; int kkg = (int)((r >> 6) & 3); int ntile = (int)(r >> 8);
    n = ntile * 16 + (lane & 15); k = kkg * 32 + ((lane >> 4) << 3);
    src = TW2 + (long)d * T1D * T2D; N = T2D;
    dst = TW2P + ((long)(d * 16 + ntile * 4 + kkg) * 64 + lane) * 8;
  } else {
    if (tid < NDOM) cnt[tid] = 0;
    return;
  }
  bf16x8 o;
#pragma unroll
  for (int e = 0; e < 8; ++e) o[e] = (__bf16)src[(long)(k + e) * N + n];
  *(bf16x8*)dst = o;
}

// ---------------------------------------------------------------------------
// Fused: gather + GEMM1 + GEMM2 per 64-row panel.
// R10: single-shot A-staging kills the 10-step barrier convoy (R9 diagnostic:
// MfmaUtil 24%, all pipes idle -> per-step barrier waited on slowest random
// gather 10x/block).  sA = full 64x640 bf16 panel (80KB); each thread issues
// its 10 random-row loads up front (20 dwordx4 in flight -> ~5120/block),
// commits to swizzled LDS as they retire, ONE barrier, then GEMM1 runs
// BARRIER-FREE (per f: 4 ds_read_b128 + 4 W1P L2-frags + 16 MFMA).
// LDS 149KB -> 1 block/CU, 8 waves (unchanged occupancy).
// ---------------------------------------------------------------------------
__global__ __launch_bounds__(512) void k_fused(const int* __restrict__ fids,
                                               const int* __restrict__ dom,
                                               const float* __restrict__ emb,
                                               const __bf16* __restrict__ W1P,
                                               const float* __restrict__ b1,
                                               const __bf16* __restrict__ W2P,
                                               const float* __restrict__ b2,
                                               __bf16* __restrict__ h2,
                                               int* __restrict__ cnt,
                                               int* __restrict__ lists) {
  __shared__ int    ids_lds[64 * F_SZ];       //  5120 B
  __shared__ __bf16 sA[64 * DBOT];            // 81920 B (swizzled rows, 1280B)
  __shared__ __bf16 h1[64 * D1];              // 65536 B (swizzled rows, 1024B)

  int bid = blockIdx.x, tid = threadIdx.x;
  int lane = tid & 63, w = tid >> 6;
  int lrow = lane & 15, kq = lane >> 4;
  int m0 = bid * 64;

  // ---- domain partition (blocks 0-63, first 4 waves) ----
  if (bid < 64 && tid < 256) {
    int i = bid * 256 + tid;
    int d = dom[i];
    int pl = tid & 63;
#pragma unroll
    for (int dd = 0; dd < NDOM; ++dd) {
      unsigned long long md = __ballot(d == dd);
      if (d == dd) {
        int myoff = __popcll(md & ((1ull << pl) - 1ull));
        int leader = __ffsll((long long)md) - 1;
        int base = 0;
        if (pl == leader) base = atomicAdd(&cnt[dd], __popcll(md));
        base = __shfl(base, leader);
        lists[dd * B_SZ + base + myoff] = i;
      }
    }
  }

  // ---- stage feature ids ----
  for (int i = tid; i < 64 * F_SZ; i += 512) ids_lds[i] = fids[m0 * F_SZ + i];
  __syncthreads();

  // ---- single-shot gather: 5120 chunks (row, 8-elem) / 512 thr = 10 each.
  // chunk c: row = c/80, cc = c%80 -> feature f = cc>>2, elems (cc&3)*8.
  // LDS byte = row*1280 + cc*16, XOR-swizzled by row&7.  All 10 (x2 float4)
  // loads issued up front; in-order vmcnt drains pipeline the commits.
  float4 ga[10], gb[10];
  int sb[10];
  {
#pragma unroll
    for (int i = 0; i < 10; ++i) {
      unsigned c = tid + i * 512;
      unsigned row = c / 80;
      unsigned cc = c - row * 80;
      int f = cc >> 2, es = (cc & 3) << 3;
      int id = ids_lds[row * F_SZ + f];
      const float* p = emb + ((long)f * V_SZ + id) * E_SZ + es;
      ga[i] = *(const float4*)p;
      gb[i] = *(const float4*)(p + 4);
      sb[i] = (int)(row * 1280 + cc * 16) ^ ((row & 7) << 4);
    }
#pragma unroll
    for (int i = 0; i < 10; ++i) {
      bf16x8 o;
      o[0] = (__bf16)ga[i].x; o[1] = (__bf16)ga[i].y;
      o[2] = (__bf16)ga[i].z; o[3] = (__bf16)ga[i].w;
      o[4] = (__bf16)gb[i].x; o[5] = (__bf16)gb[i].y;
      o[6] = (__bf16)gb[i].z; o[7] = (__bf16)gb[i].w;
      *(bf16x8*)((char*)sA + sb[i]) = o;
    }
  }
  __syncthreads();   // the ONE staging barrier

  // ---- GEMM1 (barrier-free): h1[64x512] = relu(A @ W1 + b1) ----
  f32x4 acc[4][4] = {};
#pragma unroll
  for (int f = 0; f < F_SZ; ++f) {
    bf16x8 af[4];
#pragma unroll
    for (int mi = 0; mi < 4; ++mi) {
      int byte = ((mi * 16 + lrow) * 1280 + (f * 32 + kq * 8) * 2) ^ ((lrow & 7) << 4);
      af[mi] = *(const bf16x8*)((const char*)sA + byte);
    }
#pragma unroll
    for (int ni = 0; ni < 4; ++ni) {
      bf16x8 bfr = *(const bf16x8*)(W1P +
          ((long)((w * 4 + ni) * 20 + f) * 64 + lane) * 8);
#pragma unroll
      for (int mi = 0; mi < 4; ++mi)
        acc[mi][ni] = MFMA(af[mi], bfr, acc[mi][ni]);
    }
  }

  // ---- h1 = relu(. + b1) -> LDS (XOR-swizzled rows, 1024B stride) ----
#pragma unroll
  for (int ni = 0; ni < 4; ++ni) {
    int col = w * 64 + ni * 16 + lrow;
    float bv = b1[col];
#pragma unroll
    for (int mi = 0; mi < 4; ++mi) {
#pragma unroll
      for (int r = 0; r < 4; ++r) {
        int row = mi * 16 + kq * 4 + r;
        float v = acc[mi][ni][r] + bv;
        v = v > 0.f ? v : 0.f;
        int byte = (row * 1024 + col * 2) ^ ((row & 7) << 4);
        *(__bf16*)((char*)h1 + byte) = (__bf16)v;
      }
    }
  }
  __syncthreads();

  // ---- GEMM2 (barrier-free): h2 = relu(h1 @ W2 + b2), K=512 ----
  f32x4 acc2[4][2] = {};
#pragma unroll 4
  for (int kkg = 0; kkg < 16; ++kkg) {
    bf16x8 a2[4];
#pragma unroll
    for (int mi = 0; mi < 4; ++mi) {
      int byte = ((mi * 16 + lrow) * 1024 + kkg * 64 + kq * 16) ^ ((lrow & 7) << 4);
      a2[mi] = *(const bf16x8*)((const char*)h1 + byte);
    }
#pragma unroll
    for (int ni = 0; ni < 2; ++ni) {
      bf16x8 bfr = *(const bf16x8*)(W2P +
          ((long)((w * 2 + ni) * 16 + kkg) * 64 + lane) * 8);
#pragma unroll
      for (int mi = 0; mi < 4; ++mi)
        acc2[mi][ni] = MFMA(a2[mi], bfr, acc2[mi][ni]);
    }
  }

  // ---- h2 store (bf16, bias+relu) ----
#pragma unroll
  for (int ni = 0; ni < 2; ++ni) {
    int col = w * 32 + ni * 16 + lrow;
    float bv = b2[col];
#pragma unroll
    for (int mi = 0; mi < 4; ++mi) {
#pragma unroll
      for (int r = 0; r < 4; ++r) {
        long row = m0 + mi * 16 + kq * 4 + r;
        float v = acc2[mi][ni][r] + bv;
        v = v > 0.f ? v : 0.f;
        h2[row * D2 + col] = (__bf16)v;
      }
    }
  }
}

// ---------------------------------------------------------------------------
// Tower (domain-partitioned): unchanged.
// ---------------------------------------------------------------------------
__global__ __launch_bounds__(256) void k_tower(const __bf16* __restrict__ h2,
                                               const __bf16* __restrict__ TW1P,
                                               const __bf16* __restrict__ TW2P,
                                               const float* __restrict__ Tb1,
                                               const float* __restrict__ Tb2,
                                               const float* __restrict__ TW3,
                                               const float* __restrict__ Tb3,
                                               const int* __restrict__ cnt,
                                               const int* __restrict__ lists,
                                               float* __restrict__ out) {
  __shared__ __bf16 t_lds[4][16 * 128];
  int d  = blockIdx.y;
  int nc = cnt[d];
  int base = blockIdx.x * 64;
  if (base >= nc) return;

  int tid  = threadIdx.x;
  int lane = tid & 63;
  int w    = tid >> 6;
  int row  = lane & 15;
  int kq   = lane >> 4;
  int slot = base + w * 16 + row;
  bool valid = slot < nc;
  int m0r = lists[d * B_SZ + (valid ? slot : 0)];

  bf16x8 a1[8];
#pragma unroll
  for (int kk = 0; kk < 8; ++kk)
    a1[kk] = *(const bf16x8*)(h2 + (long)m0r * D2 + kk * 32 + kq * 8);

  f32x4 acc1[8] = {};
#pragma unroll
  for (int kk = 0; kk < 8; ++kk) {
#pragma unroll
    for (int ni = 0; ni < 8; ++ni) {
      bf16x8 b = *(const bf16x8*)(TW1P +
          ((long)(d * 64 + ni * 8 + kk) * 64 + lane) * 8);
      acc1[ni] = MFMA(a1[kk], b, acc1[ni]);
    }
  }
#pragma unroll
  for (int ni = 0; ni < 8; ++ni) {
    float bv = Tb1[d * T1D + ni * 16 + row];
#pragma unroll
    for (int r = 0; r < 4; ++r) {
      float v = acc1[ni][r] + bv;
      v = v > 0.f ? v : 0.f;
      t_lds[w][(kq * 4 + r) * 128 + ni * 16 + row] = (__bf16)v;
    }
  }
  asm volatile("s_waitcnt lgkmcnt(0)" ::: "memory");

  bf16x8 a2[4];
#pragma unroll
  for (int kk = 0; kk < 4; ++kk)
    a2[kk] = *(const bf16x8*)(&t_lds[w][row * 128 + kk * 32 + kq * 8]);
  f32x4 acc2[4] = {};
#pragma unroll
  for (int kk = 0; kk < 4; ++kk) {
#pragma unroll
    for (int ni = 0; ni < 4; ++ni) {
      bf16x8 b = *(const bf16x8*)(TW2P +
          ((long)(d * 16 + ni * 4 + kk) * 64 + lane) * 8);
      acc2[ni] = MFMA(a2[kk], b, acc2[ni]);
    }
  }
  asm volatile("s_waitcnt lgkmcnt(0)" ::: "memory");
#pragma unroll
  for (int ni = 0; ni < 4; ++ni) {
    float bv = Tb2[d * T2D + ni * 16 + row];
#pragma unroll
    for (int r = 0; r < 4; ++r) {
      float v = acc2[ni][r] + bv;
      v = v > 0.f ? v : 0.f;
      t_lds[w][(kq * 4 + r) * 64 + ni * 16 + row] = (__bf16)v;
    }
  }
  asm volatile("s_waitcnt lgkmcnt(0)" ::: "memory");

  float s = 0.f;
#pragma unroll
  for (int j = 0; j < 16; ++j)
    s += (float)t_lds[w][row * 64 + kq * 16 + j] * TW3[d * T2D + kq * 16 + j];
  s += __shfl_xor(s, 16);
  s += __shfl_xor(s, 32);
  s += Tb3[d];
  if (valid && kq == 0)
    out[m0r] = 1.0f / (1.0f + expf(-s));
}

// ---------------------------------------------------------------------------
extern "C" void kernel_launch(void* const* d_in, const int* in_sizes, int n_in,
                              void* d_out, int out_size, void* d_ws, size_t ws_size,
                              hipStream_t stream) {
  const int*   fids = (const int*)d_in[0];
  const int*   dom  = (const int*)d_in[1];
  const float* emb  = (const float*)d_in[2];
  const float* W1   = (const float*)d_in[3];
  const float* b1   = (const float*)d_in[4];
  const float* W2   = (const float*)d_in[5];
  const float* b2   = (const float*)d_in[6];
  const float* TW1  = (const float*)d_in[7];
  const float* Tb1  = (const float*)d_in[8];
  const float* TW2  = (const float*)d_in[9];
  const float* Tb2  = (const float*)d_in[10];
  const float* TW3  = (const float*)d_in[11];
  const float* Tb3  = (const float*)d_in[12];
  float* out = (float*)d_out;

  char* ws = (char*)d_ws;
  __bf16* W1P   = (__bf16*)(ws);                 // 655360
  __bf16* W2P   = (__bf16*)(ws + 655360);        // 262144
  __bf16* TW1P  = (__bf16*)(ws + 917504);        // 262144
  __bf16* TW2P  = (__bf16*)(ws + 1179648);       // 65536
  __bf16* h2    = (__bf16*)(ws + 1245184);       // 8388608
  int*    lists = (int*)(ws + 9633792);          // 262144
  int*    cnt   = (int*)(ws + 9895936);          // 16

  k_prep<<<305, 256, 0, stream>>>(W1, W2, TW1, TW2, W1P, W2P, TW1P, TW2P, cnt);
  k_fused<<<256, 512, 0, stream>>>(fids, dom, emb, W1P, b1, W2P, b2, h2,
                                   cnt, lists);
  k_tower<<<dim3(80, NDOM), 256, 0, stream>>>(h2, TW1P, TW2P, Tb1, Tb2,
                                              TW3, Tb3, cnt, lists, out);
}

// Round 11
// 50.028 us; speedup vs baseline: 5.4480x; 1.0627x over previous
//
#include <hip/hip_runtime.h>

#define B_SZ  16384
#define F_SZ  20
#define V_SZ  100000
#define E_SZ  32
#define DBOT  640
#define D1    512
#define D2    256
#define T1D   128
#define T2D   64
#define NDOM  4

typedef __bf16 bf16x8 __attribute__((ext_vector_type(8)));
typedef float  f32x4  __attribute__((ext_vector_type(4)));

#define MFMA(a, b, c) __builtin_amdgcn_mfma_f32_16x16x32_bf16((a), (b), (c), 0, 0, 0)

// ---------------------------------------------------------------------------
// Prep: pack all weights into MFMA-fragment order bf16 (as before, minus cnt).
// ---------------------------------------------------------------------------
__global__ __launch_bounds__(256) void k_prep(const float* __restrict__ W1,
                                              const float* __restrict__ W2,
                                              const float* __restrict__ TW1,
                                              const float* __restrict__ TW2,
                                              __bf16* __restrict__ W1P,
                                              __bf16* __restrict__ W2P,
                                              __bf16* __restrict__ TW1P,
                                              __bf16* __restrict__ TW2P) {
  int bid = blockIdx.x, tid = threadIdx.x;
  const float* src; __bf16* dst; int n, k, N;
  if (bid < 160) {
    long g = (long)bid * 256 + tid;
    int lane = g & 63; int kkg = (int)((g >> 6) % 20); int ntile = (int)(g / 1280);
    n = ntile * 16 + (lane & 15); k = kkg * 32 + ((lane >> 4) << 3);
    src = W1; N = D1; dst = W1P + g * 8;
  } else if (bid < 224) {
    long g = (long)(bid - 160) * 256 + tid;
    int lane = g & 63; int kkg = (int)((g >> 6) & 15); int ntile = (int)(g >> 10);
    n = ntile * 16 + (lane & 15); k = kkg * 32 + ((lane >> 4) << 3);
    src = W2; N = D2; dst = W2P + g * 8;
  } else if (bid < 288) {
    long g = (long)(bid - 224) * 256 + tid;
    int d = (int)(g >> 12); long r = g & 4095;
    int lane = r & 63; int kkg = (int)((r >> 6) & 7); int ntile = (int)(r >> 9);
    n = ntile * 16 + (lane & 15); k = kkg * 32 + ((lane >> 4) << 3);
    src = TW1 + (long)d * D2 * T1D; N = T1D;
    dst = TW1P + ((long)(d * 64 + ntile * 8 + kkg) * 64 + lane) * 8;
  } else {
    long g = (long)(bid - 288) * 256 + tid;
    int d = (int)(g >> 10); long r = g & 1023;
    int lane = r & 63; int kkg = (int)((r >> 6) & 3); int ntile = (int)(r >> 8);
    n = ntile * 16 + (lane & 15); k = kkg * 32 + ((lane >> 4) << 3);
    src = TW2 + (long)d * T1D * T2D; N = T2D;
    dst = TW2P + ((long)(d * 16 + ntile * 4 + kkg) * 64 + lane) * 8;
  }
  bf16x8 o;
#pragma unroll
  for (int e = 0; e < 8; ++e) o[e] = (__bf16)src[(long)(k + e) * N + n];
  *(bf16x8*)dst = o;
}

// ---------------------------------------------------------------------------
// MEGAFUSED: gather + GEMM1 + GEMM2 + 4-domain tower + sigmoid + select,
// one block = 64 rows end-to-end.  Tower is per-row independent, so the
// domain partition (and k_tower launch, h2 global round-trip, lists/cnt)
// are deleted; all 4 domains computed (+2.2us MFMA chip-wide -- R2 showed
// partitioning saved ~nothing).  Waves 0-3: rows x domains {0,1};
// waves 4-7: rows x domains {2,3}; the unique (row,domain) match stores.
// LDS: ids 5K | sA 80K (reused for h2 32K + t_lds 32K after GEMM1) | h1 64K.
// ---------------------------------------------------------------------------
__global__ __launch_bounds__(512) void k_mega(const int* __restrict__ fids,
                                              const int* __restrict__ dom,
                                              const float* __restrict__ emb,
                                              const __bf16* __restrict__ W1P,
                                              const float* __restrict__ b1,
                                              const __bf16* __restrict__ W2P,
                                              const float* __restrict__ b2,
                                              const __bf16* __restrict__ TW1P,
                                              const __bf16* __restrict__ TW2P,
                                              const float* __restrict__ Tb1,
                                              const float* __restrict__ Tb2,
                                              const float* __restrict__ TW3,
                                              const float* __restrict__ Tb3,
                                              float* __restrict__ out) {
  __shared__ __attribute__((aligned(16))) char smem[152576];
  int*    ids_lds = (int*)(smem + 147456);        // 5120B  (tail)
  __bf16* sA      = (__bf16*)smem;                // 81920B (rows 1280B, swz)
  __bf16* h1      = (__bf16*)(smem + 81920);      // 65536B (rows 1024B, swz)
  __bf16* h2_lds  = (__bf16*)smem;                // 32768B (rows 512B, swz)
  __bf16* t_lds   = (__bf16*)(smem + 32768);      // 32768B (8 waves x 4KB)

  int bid = blockIdx.x, tid = threadIdx.x;
  int lane = tid & 63, w = tid >> 6;
  int lrow = lane & 15, kq = lane >> 4;
  int m0 = bid * 64;

  // ---- stage feature ids ----
  for (int i = tid; i < 64 * F_SZ; i += 512) ids_lds[i] = fids[m0 * F_SZ + i];
  __syncthreads();

  // ---- single-shot gather: 5120 (row, 8-elem) chunks / 512 thr = 10 each ----
  {
    float4 ga[10], gb[10];
    int sb[10];
#pragma unroll
    for (int i = 0; i < 10; ++i) {
      unsigned c = tid + i * 512;
      unsigned row = c / 80;
      unsigned cc = c - row * 80;
      int f = cc >> 2, es = (cc & 3) << 3;
      int id = ids_lds[row * F_SZ + f];
      const float* p = emb + ((long)f * V_SZ + id) * E_SZ + es;
      ga[i] = *(const float4*)p;
      gb[i] = *(const float4*)(p + 4);
      sb[i] = (int)(row * 1280 + cc * 16) ^ ((row & 7) << 4);
    }
#pragma unroll
    for (int i = 0; i < 10; ++i) {
      bf16x8 o;
      o[0] = (__bf16)ga[i].x; o[1] = (__bf16)ga[i].y;
      o[2] = (__bf16)ga[i].z; o[3] = (__bf16)ga[i].w;
      o[4] = (__bf16)gb[i].x; o[5] = (__bf16)gb[i].y;
      o[6] = (__bf16)gb[i].z; o[7] = (__bf16)gb[i].w;
      *(bf16x8*)((char*)sA + sb[i]) = o;
    }
  }
  __syncthreads();

  // ---- GEMM1 (barrier-free): h1[64x512] = relu(A @ W1 + b1) ----
  {
    f32x4 acc[4][4] = {};
#pragma unroll
    for (int f = 0; f < F_SZ; ++f) {
      bf16x8 af[4];
#pragma unroll
      for (int mi = 0; mi < 4; ++mi) {
        int byte = ((mi * 16 + lrow) * 1280 + (f * 32 + kq * 8) * 2) ^ ((lrow & 7) << 4);
        af[mi] = *(const bf16x8*)((const char*)sA + byte);
      }
#pragma unroll
      for (int ni = 0; ni < 4; ++ni) {
        bf16x8 bfr = *(const bf16x8*)(W1P +
            ((long)((w * 4 + ni) * 20 + f) * 64 + lane) * 8);
#pragma unroll
        for (int mi = 0; mi < 4; ++mi)
          acc[mi][ni] = MFMA(af[mi], bfr, acc[mi][ni]);
      }
    }
#pragma unroll
    for (int ni = 0; ni < 4; ++ni) {
      int col = w * 64 + ni * 16 + lrow;
      float bv = b1[col];
#pragma unroll
      for (int mi = 0; mi < 4; ++mi) {
#pragma unroll
        for (int r = 0; r < 4; ++r) {
          int row = mi * 16 + kq * 4 + r;
          float v = acc[mi][ni][r] + bv;
          v = v > 0.f ? v : 0.f;
          int byte = (row * 1024 + col * 2) ^ ((row & 7) << 4);
          *(__bf16*)((char*)h1 + byte) = (__bf16)v;
        }
      }
    }
  }
  __syncthreads();   // h1 complete; sA region dead -> reusable

  // ---- GEMM2 (barrier-free): h2[64x256] = relu(h1 @ W2 + b2) -> LDS ----
  {
    f32x4 acc2[4][2] = {};
#pragma unroll 4
    for (int kkg = 0; kkg < 16; ++kkg) {
      bf16x8 a2[4];
#pragma unroll
      for (int mi = 0; mi < 4; ++mi) {
        int byte = ((mi * 16 + lrow) * 1024 + kkg * 64 + kq * 16) ^ ((lrow & 7) << 4);
        a2[mi] = *(const bf16x8*)((const char*)h1 + byte);
      }
#pragma unroll
      for (int ni = 0; ni < 2; ++ni) {
        bf16x8 bfr = *(const bf16x8*)(W2P +
            ((long)((w * 2 + ni) * 16 + kkg) * 64 + lane) * 8);
#pragma unroll
        for (int mi = 0; mi < 4; ++mi)
          acc2[mi][ni] = MFMA(a2[mi], bfr, acc2[mi][ni]);
      }
    }
    // h2 -> LDS (rows 512B, swizzled by row&7)
#pragma unroll
    for (int ni = 0; ni < 2; ++ni) {
      int col = w * 32 + ni * 16 + lrow;
      float bv = b2[col];
#pragma unroll
      for (int mi = 0; mi < 4; ++mi) {
#pragma unroll
        for (int r = 0; r < 4; ++r) {
          int row = mi * 16 + kq * 4 + r;
          float v = acc2[mi][ni][r] + bv;
          v = v > 0.f ? v : 0.f;
          int byte = (row * 512 + col * 2) ^ ((row & 7) << 4);
          *(__bf16*)((char*)h2_lds + byte) = (__bf16)v;
        }
      }
    }
  }
  __syncthreads();   // h2 complete (all waves' column slices)

  // ---- Tower: wave w -> rows (w&3)*16 .. +15, domains {2*(w>>2), +1} ----
  {
    int r0 = (w & 3) * 16;
    int d0 = (w >> 2) * 2;
    int grow = r0 + lrow;                 // this lane's row (0..63)
    int mydom = dom[m0 + grow];
    __bf16* tw = t_lds + w * 2048;        // per-wave 16x128 scratch

    // a1 fragments from h2_lds
    bf16x8 a1[8];
#pragma unroll
    for (int kk = 0; kk < 8; ++kk) {
      int byte = (grow * 512 + (kk * 32 + kq * 8) * 2) ^ ((grow & 7) << 4);
      a1[kk] = *(const bf16x8*)((const char*)h2_lds + byte);
    }

#pragma unroll
    for (int dd = 0; dd < 2; ++dd) {
      int d = d0 + dd;
      // t1 = relu(h2 @ TW1[d] + Tb1[d])  (16 x 128)
      f32x4 acc1[8] = {};
#pragma unroll
      for (int kk = 0; kk < 8; ++kk) {
#pragma unroll
        for (int ni = 0; ni < 8; ++ni) {
          bf16x8 b = *(const bf16x8*)(TW1P +
              ((long)(d * 64 + ni * 8 + kk) * 64 + lane) * 8);
          acc1[ni] = MFMA(a1[kk], b, acc1[ni]);
        }
      }
#pragma unroll
      for (int ni = 0; ni < 8; ++ni) {
        float bv = Tb1[d * T1D + ni * 16 + lrow];
#pragma unroll
        for (int r = 0; r < 4; ++r) {
          float v = acc1[ni][r] + bv;
          v = v > 0.f ? v : 0.f;
          tw[(kq * 4 + r) * 128 + ni * 16 + lrow] = (__bf16)v;
        }
      }
      asm volatile("s_waitcnt lgkmcnt(0)" ::: "memory");

      // t2 = relu(t1 @ TW2[d] + Tb2[d])  (16 x 64)
      bf16x8 a2f[4];
#pragma unroll
      for (int kk = 0; kk < 4; ++kk)
        a2f[kk] = *(const bf16x8*)(&tw[lrow * 128 + kk * 32 + kq * 8]);
      f32x4 acc2[4] = {};
#pragma unroll
      for (int kk = 0; kk < 4; ++kk) {
#pragma unroll
        for (int ni = 0; ni < 4; ++ni) {
          bf16x8 b = *(const bf16x8*)(TW2P +
              ((long)(d * 16 + ni * 4 + kk) * 64 + lane) * 8);
          acc2[ni] = MFMA(a2f[kk], b, acc2[ni]);
        }
      }
      asm volatile("s_waitcnt lgkmcnt(0)" ::: "memory");
#pragma unroll
      for (int ni = 0; ni < 4; ++ni) {
        float bv = Tb2[d * T2D + ni * 16 + lrow];
#pragma unroll
        for (int r = 0; r < 4; ++r) {
          float v = acc2[ni][r] + bv;
          v = v > 0.f ? v : 0.f;
          tw[(kq * 4 + r) * 64 + ni * 16 + lrow] = (__bf16)v;
        }
      }
      asm volatile("s_waitcnt lgkmcnt(0)" ::: "memory");

      // logit + sigmoid + select-store
      float s = 0.f;
#pragma unroll
      for (int j = 0; j < 16; ++j)
        s += (float)tw[lrow * 64 + kq * 16 + j] * TW3[d * T2D + kq * 16 + j];
      s += __shfl_xor(s, 16);
      s += __shfl_xor(s, 32);
      s += Tb3[d];
      if (kq == 0 && mydom == d)
        out[m0 + grow] = 1.0f / (1.0f + expf(-s));
      asm volatile("s_waitcnt lgkmcnt(0)" ::: "memory");  // tw reuse next d
    }
  }
}

// ---------------------------------------------------------------------------
extern "C" void kernel_launch(void* const* d_in, const int* in_sizes, int n_in,
                              void* d_out, int out_size, void* d_ws, size_t ws_size,
                              hipStream_t stream) {
  const int*   fids = (const int*)d_in[0];
  const int*   dom  = (const int*)d_in[1];
  const float* emb  = (const float*)d_in[2];
  const float* W1   = (const float*)d_in[3];
  const float* b1   = (const float*)d_in[4];
  const float* W2   = (const float*)d_in[5];
  const float* b2   = (const float*)d_in[6];
  const float* TW1  = (const float*)d_in[7];
  const float* Tb1  = (const float*)d_in[8];
  const float* TW2  = (const float*)d_in[9];
  const float* Tb2  = (const float*)d_in[10];
  const float* TW3  = (const float*)d_in[11];
  const float* Tb3  = (const float*)d_in[12];
  float* out = (float*)d_out;

  char* ws = (char*)d_ws;
  __bf16* W1P   = (__bf16*)(ws);                 // 655360
  __bf16* W2P   = (__bf16*)(ws + 655360);        // 262144
  __bf16* TW1P  = (__bf16*)(ws + 917504);        // 262144
  __bf16* TW2P  = (__bf16*)(ws + 1179648);       // 65536

  k_prep<<<304, 256, 0, stream>>>(W1, W2, TW1, TW2, W1P, W2P, TW1P, TW2P);
  k_mega<<<256, 512, 0, stream>>>(fids, dom, emb, W1P, b1, W2P, b2,
                                  TW1P, TW2P, Tb1, Tb2, TW3, Tb3, out);
}